// Round 4
// baseline (168.369 us; speedup 1.0000x reference)
//
#include <hip/hip_runtime.h>
#include <hip/hip_cooperative_groups.h>

namespace cg = cooperative_groups;

// ---------------------------------------------------------------------------
// StateIntegratorND: 41984 pts (1024 x 41 sigma pts), drift =
// MLP(20->128->128->16, tanh), forward Euler, h=DT=0.01 (1 eval).
// Euler LTE (h^2/2)|Jf| <= ~5e-4 at the output (UT-averaged), below bf16
// noise 1.95e-3, threshold 1.46e-2.
//
// R12: SINGLE COOPERATIVE DISPATCH. R11 (77.8us) = ~40.4us harness poison
// fill + 9 small fills + ~1.6us/dispatch slots + integ(~5us) + prep(~1us).
// Only controllable residue: prep's dispatch slot + exec. So merge:
//   phase 1 (first 22528 threads): weight transpose/prescale into d_ws
//            + zero out[] (identical math to R11's prep_kernel)
//   grid.sync()   (656 blocks, all co-resident at 4 blocks/CU: 656 <= 1024)
//   phase 2: R11's integ body VERBATIM.
// Fallback: if hipLaunchCooperativeKernel is rejected, launch R11's proven
// two-dispatch path (prep_kernel + integ_plain) instead.
//
// MFMA 16x16x32 bf16 layouts (verified m89/m91):
//   A[m=lane&15][k=(lane>>4)*8+j]  (A = W^T: m = unit)
//   B[k=(lane>>4)*8+j][n=lane&15]  (n = point)
//   D[row=(lane>>4)*4+r][col=lane&15]
// W1/b1/W2/b2 pre-scaled by 2*log2(e): tanh(p) = 1 - 2/(exp2(ps)+1).
//
// d_ws layout (bf16): [0..16383] W2T[u][k] (=W2[k][u]*S)
//                     [16384..20479] W1T[u][k0..31] (k=20 row = b1*S, 21..31=0)
//                     [20480..22527] W3T[c][k] (=W3[k][c], unscaled)
// ---------------------------------------------------------------------------

typedef float  f32x4  __attribute__((ext_vector_type(4)));
typedef __bf16 bf16x8 __attribute__((ext_vector_type(8)));
typedef __bf16 bf16x2 __attribute__((ext_vector_type(2)));

#define DT 0.01
#define TANH_SCALE 2.885390081777926814f   // 2*log2(e)

__device__ inline unsigned int pack2(float a, float b) {
    bf16x2 v;
    v[0] = (__bf16)a;
    v[1] = (__bf16)b;
    return __builtin_bit_cast(unsigned int, v);
}

__device__ inline float tanh_pre(float xs) {
    float t = __builtin_amdgcn_exp2f(xs);
    float r = __builtin_amdgcn_rcpf(t + 1.0f);
    return __builtin_fmaf(-2.0f, r, 1.0f);
}

__device__ inline bf16x8 as_frag(uint4 u) { return __builtin_bit_cast(bf16x8, u); }

// One drift eval over scalars only (identical to the R4-passing macro).
// Uses enclosing names: xs_t,h1_t,h2_t,wrow,q,c,wave,w1f,w2f,w3f,b2s0,b2s1,b3s.
#define FEVAL(XI0, XI1, XI2, XI3, O0, O1, O2, O3) do {                        \
    *(uint2*)&xs_t[wrow][2 * q] =                                             \
        make_uint2(pack2((XI0), (XI1)), pack2((XI2), (XI3)));                 \
    __syncthreads();   /* BAR: xs visible */                                  \
    f32x4 acc_[2][4];                                                         \
    {                                                                         \
        bf16x8 bx_[4];                                                        \
        _Pragma("unroll") for (int nt = 0; nt < 4; ++nt)                      \
            bx_[nt] = as_frag(*(const uint4*)&xs_t[nt * 16 + c][4 * q]);      \
        _Pragma("unroll") for (int mt = 0; mt < 2; ++mt)                      \
        _Pragma("unroll") for (int nt = 0; nt < 4; ++nt) {                    \
            f32x4 z_ = {0.0f, 0.0f, 0.0f, 0.0f};                              \
            acc_[mt][nt] = __builtin_amdgcn_mfma_f32_16x16x32_bf16(           \
                w1f[mt], bx_[nt], z_, 0, 0, 0);                               \
        }                                                                     \
    }                                                                         \
    _Pragma("unroll") for (int mt = 0; mt < 2; ++mt)                          \
    _Pragma("unroll") for (int nt = 0; nt < 4; ++nt) {                        \
        *(uint2*)&h1_t[nt * 16 + c][16 * wave + 8 * mt + 2 * q] = make_uint2( \
            pack2(tanh_pre(acc_[mt][nt][0]), tanh_pre(acc_[mt][nt][1])),      \
            pack2(tanh_pre(acc_[mt][nt][2]), tanh_pre(acc_[mt][nt][3])));     \
    }                                                                         \
    __syncthreads();   /* BAR: h1 visible */                                  \
    _Pragma("unroll") for (int nt = 0; nt < 4; ++nt) {                        \
        acc_[0][nt] = b2s0;                                                   \
        acc_[1][nt] = b2s1;                                                   \
    }                                                                         \
    _Pragma("unroll") for (int ks = 0; ks < 4; ++ks) {                        \
        bf16x8 bh_[4];                                                        \
        _Pragma("unroll") for (int nt = 0; nt < 4; ++nt)                      \
            bh_[nt] = as_frag(                                                \
                *(const uint4*)&h1_t[nt * 16 + c][16 * ks + 4 * q]);          \
        _Pragma("unroll") for (int mt = 0; mt < 2; ++mt)                      \
        _Pragma("unroll") for (int nt = 0; nt < 4; ++nt)                      \
            acc_[mt][nt] = __builtin_amdgcn_mfma_f32_16x16x32_bf16(           \
                w2f[mt][ks], bh_[nt], acc_[mt][nt], 0, 0, 0);                 \
    }                                                                         \
    _Pragma("unroll") for (int mt = 0; mt < 2; ++mt)                          \
    _Pragma("unroll") for (int nt = 0; nt < 4; ++nt) {                        \
        *(uint2*)&h2_t[nt * 16 + c][16 * wave + 8 * mt + 2 * q] = make_uint2( \
            pack2(tanh_pre(acc_[mt][nt][0]), tanh_pre(acc_[mt][nt][1])),      \
            pack2(tanh_pre(acc_[mt][nt][2]), tanh_pre(acc_[mt][nt][3])));     \
    }                                                                         \
    __syncthreads();   /* BAR: h2 visible */                                  \
    {                                                                         \
        f32x4 a3_ = b3s;                                                      \
        _Pragma("unroll") for (int ks = 0; ks < 4; ++ks) {                    \
            bf16x8 bh_ = as_frag(                                             \
                *(const uint4*)&h2_t[wave * 16 + c][16 * ks + 4 * q]);        \
            a3_ = __builtin_amdgcn_mfma_f32_16x16x32_bf16(                    \
                w3f[ks], bh_, a3_, 0, 0, 0);                                  \
        }                                                                     \
        (O0) = a3_[0]; (O1) = a3_[1]; (O2) = a3_[2]; (O3) = a3_[3];           \
    }                                                                         \
} while (0)

// Weight prep + out-zero for linear index i in [0, 22528). Identical math to
// R11's prep_kernel.
__device__ __forceinline__ void prep_body(int i,
        const float* __restrict__ W1, const float* __restrict__ b1,
        const float* __restrict__ W2, const float* __restrict__ W3,
        __bf16* ws, float* out)
{
    if (i < 16384) {
        out[i] = 0.0f;
        // W2T[u][k] = W2[k][u] * S   (u = i>>7, k = i&127)
        const int u = i >> 7, k = i & 127;
        ws[i] = (__bf16)(W2[(k << 7) + u] * TANH_SCALE);
    } else if (i < 20480) {
        // W1T[u][k], k=0..31: rows 0..19 = W1*S, row 20 = b1*S, 21..31 = 0
        const int j = i - 16384;
        const int u = j >> 5, k = j & 31;
        const float v = (k < 20) ? W1[(k << 7) + u] * TANH_SCALE
                                 : ((k == 20) ? b1[u] * TANH_SCALE : 0.0f);
        ws[i] = (__bf16)v;
    } else {
        // W3T[c][k] = W3[k][c]  (c = j>>7, k = j&127), unscaled
        const int j = i - 20480;
        const int cc = j >> 7, k = j & 127;
        ws[i] = (__bf16)W3[(k << 4) + cc];
    }
}

// R11's integ body verbatim (reads prepped ws, segmented atomic UT reduce).
__device__ __forceinline__ void integ_body(
        const float* __restrict__ sp, const float* __restrict__ Wp,
        const float* __restrict__ b2, const float* __restrict__ b3,
        const __bf16* wsw, float* out)
{
    // 39936 B arena -> 4 blocks/CU (4 x 39936 = 159744 <= 163840):
    //   xs_t 0..5119 | h1_t 5120..22527 | h2_t 22528..39935
    //   [done] parts (64x20 f32) overlays h1_t region
    __shared__ __align__(16) unsigned char smem[39936];
    unsigned int (*xs_t)[20] = (unsigned int (*)[20])smem;
    unsigned int (*h1_t)[68] = (unsigned int (*)[68])(smem + 5120);
    unsigned int (*h2_t)[68] = (unsigned int (*)[68])(smem + 22528);
    float* parts = (float*)(smem + 5120);

    const int tid  = threadIdx.x;
    const int wave = tid >> 6;
    const int lane = tid & 63;
    const int q    = lane >> 4;
    const int c    = lane & 15;
    const int wrow = wave * 16 + c;
    const int pt   = blockIdx.x * 64 + wrow;   // 656*64 = 41984 exact

    // ---- early global loads ----
    const float4 xv = *(const float4*)(sp + (size_t)pt * 20 + 4 * q);
    const float4 u4 = *(const float4*)(sp + (size_t)pt * 20 + 16);
    const float  wp = Wp[pt];
    float4 t0 = *(const float4*)(b2 + 32 * wave + 4 * q);
    float4 t1 = *(const float4*)(b2 + 32 * wave + 16 + 4 * q);
    float4 t3 = *(const float4*)(b3 + 4 * q);
    const f32x4 b2s0 = {t0.x * TANH_SCALE, t0.y * TANH_SCALE,
                        t0.z * TANH_SCALE, t0.w * TANH_SCALE};
    const f32x4 b2s1 = {t1.x * TANH_SCALE, t1.y * TANH_SCALE,
                        t1.z * TANH_SCALE, t1.w * TANH_SCALE};
    const f32x4 b3s  = {t3.x, t3.y, t3.z, t3.w};

    // ---- fragment loads straight from prepped global (L2-resident) ----
    const __bf16* w2t = wsw;            // [u][k] 128x128
    const __bf16* w1t = wsw + 16384;    // [u][k] 128x32
    const __bf16* w3t = wsw + 20480;    // [c][k]  16x128

    bf16x8 w1f[2];
    bf16x8 w2f[2][4];   // 32 VGPRs
    bf16x8 w3f[4];
#pragma unroll
    for (int mt = 0; mt < 2; ++mt) {
        const int ucol = 32 * wave + 16 * mt + c;
        w1f[mt] = as_frag(*(const uint4*)&w1t[(ucol << 5) + (q << 3)]);
#pragma unroll
        for (int ks = 0; ks < 4; ++ks)
            w2f[mt][ks] =
                as_frag(*(const uint4*)&w2t[(ucol << 7) + (ks << 5) + (q << 3)]);
    }
#pragma unroll
    for (int ks = 0; ks < 4; ++ks)
        w3f[ks] = as_frag(*(const uint4*)&w3t[(c << 7) + (ks << 5) + (q << 3)]);

    // ---- static xs parts: u dims 16..19, 1.0 at dim 20, zeros 21..31 ----
    // (FEVAL's first __syncthreads covers these writes.)
    if (q == 0) {
        *(uint2*)&xs_t[wrow][8] = make_uint2(pack2(u4.x, u4.y), pack2(u4.z, u4.w));
    } else if (q == 1) {
        *(uint2*)&xs_t[wrow][10] = make_uint2(pack2(1.0f, 0.0f), 0u);
    } else if (q == 2) {
        *(uint4*)&xs_t[wrow][12] = make_uint4(0u, 0u, 0u, 0u);
    }

    // ---- forward Euler: X += h * f(X) ----
    float X0 = xv.x, X1 = xv.y, X2 = xv.z, X3 = xv.w;
    float k10, k11, k12, k13;
    FEVAL(X0, X1, X2, X3, k10, k11, k12, k13);
    X0 = __builtin_fmaf((float)DT, k10, X0);
    X1 = __builtin_fmaf((float)DT, k11, X1);
    X2 = __builtin_fmaf((float)DT, k12, X2);
    X3 = __builtin_fmaf((float)DT, k13, X3);

    // ---- segmented UT reduce: partials to LDS (h1 region is dead now) ----
    *(float4*)&parts[wrow * 20 + 4 * q] =
        make_float4(wp * X0, wp * X1, wp * X2, wp * X3);

    __syncthreads();   // BAR: partials visible

    // 64 consecutive points span <= 3 batches of 41
    if (tid < 48) {
        const int base = blockIdx.x * 64;
        const int bi = tid >> 4, d = tid & 15;
        const int batch = base / 41 + bi;
        if (batch < 1024) {
            int lo = batch * 41, hi = lo + 41;
            lo = (lo < base) ? base : lo;
            hi = (hi > base + 64) ? base + 64 : hi;
            if (lo < hi) {
                float s = 0.0f;
                for (int p = lo; p < hi; ++p) s += parts[(p - base) * 20 + d];
                atomicAdd(out + batch * 16 + d, s);
            }
        }
    }
}

// ---- single cooperative dispatch: prep -> grid.sync -> integ ----
__global__ void __launch_bounds__(256, 4)
integ_coop(const float* __restrict__ sp, const float* __restrict__ Wp,
           const float* __restrict__ W1, const float* __restrict__ b1,
           const float* __restrict__ W2, const float* __restrict__ b2,
           const float* __restrict__ W3, const float* __restrict__ b3,
           __bf16* ws, float* out)
{
    const int g = blockIdx.x * 256 + threadIdx.x;
    if (g < 22528) prep_body(g, W1, b1, W2, W3, ws, out);
    cg::this_grid().sync();
    integ_body(sp, Wp, b2, b3, ws, out);
}

// ---- fallback pair (R11's proven two-dispatch path) ----
__global__ void __launch_bounds__(256)
prep_kernel(const float* __restrict__ W1, const float* __restrict__ b1,
            const float* __restrict__ W2, const float* __restrict__ W3,
            __bf16* __restrict__ ws, float* __restrict__ out)
{
    prep_body(blockIdx.x * 256 + threadIdx.x, W1, b1, W2, W3, ws, out);
}

__global__ void __launch_bounds__(256, 4)
integ_plain(const float* __restrict__ sp, const float* __restrict__ Wp,
            const float* __restrict__ b2, const float* __restrict__ b3,
            const __bf16* __restrict__ wsw, float* __restrict__ out)
{
    integ_body(sp, Wp, b2, b3, wsw, out);
}

extern "C" void kernel_launch(void* const* d_in, const int* in_sizes, int n_in,
                              void* d_out, int out_size, void* d_ws, size_t ws_size,
                              hipStream_t stream) {
    (void)in_sizes; (void)n_in; (void)ws_size; (void)out_size;
    const float* sp = (const float*)d_in[0];
    const float* Wp = (const float*)d_in[1];
    const float* W1 = (const float*)d_in[2];
    const float* b1 = (const float*)d_in[3];
    const float* W2 = (const float*)d_in[4];
    const float* b2 = (const float*)d_in[5];
    const float* W3 = (const float*)d_in[6];
    const float* b3 = (const float*)d_in[7];
    __bf16*      ws = (__bf16*)d_ws;
    float*      out = (float*)d_out;

    void* args[] = {&sp, &Wp, &W1, &b1, &W2, &b2, &W3, &b3, &ws, &out};
    hipError_t err = hipLaunchCooperativeKernel(
        (const void*)integ_coop, dim3(656), dim3(256), args, 0, stream);
    if (err != hipSuccess) {
        // capture/runtime refused cooperative launch -> R11 path
        prep_kernel<<<dim3(88), dim3(256), 0, stream>>>(W1, b1, W2, W3, ws, out);
        integ_plain<<<dim3(656), dim3(256), 0, stream>>>(sp, Wp, b2, b3, ws, out);
    }
}

// Round 5
// 77.458 us; speedup vs baseline: 2.1737x; 2.1737x over previous
//
#include <hip/hip_runtime.h>

// ---------------------------------------------------------------------------
// StateIntegratorND: 41984 pts (1024 x 41 sigma pts), drift =
// MLP(20->128->128->16, tanh), forward Euler, h=DT=0.01 (1 eval).
// Euler LTE (h^2/2)|Jf| <= ~5e-4 at the output (UT-averaged), below bf16
// noise 1.95e-3, threshold 1.46e-2.
//
// R13 = R11 restored (best measured: 77.79us). Structural post-mortems:
//  - R10: single dispatch w/ per-block redundant weight gather: +13us. DEAD.
//  - R12: single cooperative dispatch w/ grid.sync: the grid barrier alone
//    costs ~80us on MI355X (656 blocks across 8 non-coherent XCD L2s;
//    integ_coop measured 84us with MfmaUtil 0.8%, VALUBusy 2.8%). DEAD.
//  - R12 side-catch: SQ_LDS_BANK_CONFLICT ~446K total ~= 0.7us -- FEVAL's
//    LDS conflicts are negligible, no lever there.
// Remaining structure: 12 dispatches/iter = 10 harness poison fills (one
// 256MiB at ~83% HBM peak -- its own roofline) + prep + integ. Controllable
// residue ~2.5us; both merge routes measured and refuted.
//
//  - prep_kernel writes W1/W2/W3 into d_ws in FRAGMENT ORDER (bf16,
//    pre-scaled by 2*log2(e)) and zeroes the 16384-float output.
//  - integ loads all MFMA A-fragments with 14 global_load_dwordx4 from L2.
//  - LDS arena = xs(5120) + h1(17408) + h2(17408) = 39936 B -> 4 blocks/CU.
//  - __launch_bounds__(256,4) pins VGPR<=128.
//
// MFMA 16x16x32 bf16 layouts (verified m89/m91):
//   A[m=lane&15][k=(lane>>4)*8+j]  (A = W^T: m = unit)
//   B[k=(lane>>4)*8+j][n=lane&15]  (n = point)
//   D[row=(lane>>4)*4+r][col=lane&15]
// W1/b1/W2/b2 pre-scaled by 2*log2(e): tanh(p) = 1 - 2/(exp2(ps)+1).
//
// d_ws layout (bf16): [0..16383] W2T[u][k] (=W2[k][u]*S)
//                     [16384..20479] W1T[u][k0..31] (k=20 row = b1*S, 21..31=0)
//                     [20480..22527] W3T[c][k] (=W3[k][c], unscaled)
// ---------------------------------------------------------------------------

typedef float  f32x4  __attribute__((ext_vector_type(4)));
typedef __bf16 bf16x8 __attribute__((ext_vector_type(8)));
typedef __bf16 bf16x2 __attribute__((ext_vector_type(2)));

#define DT 0.01
#define TANH_SCALE 2.885390081777926814f   // 2*log2(e)

__device__ inline unsigned int pack2(float a, float b) {
    bf16x2 v;
    v[0] = (__bf16)a;
    v[1] = (__bf16)b;
    return __builtin_bit_cast(unsigned int, v);
}

__device__ inline float tanh_pre(float xs) {
    float t = __builtin_amdgcn_exp2f(xs);
    float r = __builtin_amdgcn_rcpf(t + 1.0f);
    return __builtin_fmaf(-2.0f, r, 1.0f);
}

__device__ inline bf16x8 as_frag(uint4 u) { return __builtin_bit_cast(bf16x8, u); }

// One drift eval over scalars only (identical to the R4-passing macro).
// Uses enclosing names: xs_t,h1_t,h2_t,wrow,q,c,wave,w1f,w2f,w3f,b2s0,b2s1,b3s.
#define FEVAL(XI0, XI1, XI2, XI3, O0, O1, O2, O3) do {                        \
    *(uint2*)&xs_t[wrow][2 * q] =                                             \
        make_uint2(pack2((XI0), (XI1)), pack2((XI2), (XI3)));                 \
    __syncthreads();   /* BAR: xs visible */                                  \
    f32x4 acc_[2][4];                                                         \
    {                                                                         \
        bf16x8 bx_[4];                                                        \
        _Pragma("unroll") for (int nt = 0; nt < 4; ++nt)                      \
            bx_[nt] = as_frag(*(const uint4*)&xs_t[nt * 16 + c][4 * q]);      \
        _Pragma("unroll") for (int mt = 0; mt < 2; ++mt)                      \
        _Pragma("unroll") for (int nt = 0; nt < 4; ++nt) {                    \
            f32x4 z_ = {0.0f, 0.0f, 0.0f, 0.0f};                              \
            acc_[mt][nt] = __builtin_amdgcn_mfma_f32_16x16x32_bf16(           \
                w1f[mt], bx_[nt], z_, 0, 0, 0);                               \
        }                                                                     \
    }                                                                         \
    _Pragma("unroll") for (int mt = 0; mt < 2; ++mt)                          \
    _Pragma("unroll") for (int nt = 0; nt < 4; ++nt) {                        \
        *(uint2*)&h1_t[nt * 16 + c][16 * wave + 8 * mt + 2 * q] = make_uint2( \
            pack2(tanh_pre(acc_[mt][nt][0]), tanh_pre(acc_[mt][nt][1])),      \
            pack2(tanh_pre(acc_[mt][nt][2]), tanh_pre(acc_[mt][nt][3])));     \
    }                                                                         \
    __syncthreads();   /* BAR: h1 visible */                                  \
    _Pragma("unroll") for (int nt = 0; nt < 4; ++nt) {                        \
        acc_[0][nt] = b2s0;                                                   \
        acc_[1][nt] = b2s1;                                                   \
    }                                                                         \
    _Pragma("unroll") for (int ks = 0; ks < 4; ++ks) {                        \
        bf16x8 bh_[4];                                                        \
        _Pragma("unroll") for (int nt = 0; nt < 4; ++nt)                      \
            bh_[nt] = as_frag(                                                \
                *(const uint4*)&h1_t[nt * 16 + c][16 * ks + 4 * q]);          \
        _Pragma("unroll") for (int mt = 0; mt < 2; ++mt)                      \
        _Pragma("unroll") for (int nt = 0; nt < 4; ++nt)                      \
            acc_[mt][nt] = __builtin_amdgcn_mfma_f32_16x16x32_bf16(           \
                w2f[mt][ks], bh_[nt], acc_[mt][nt], 0, 0, 0);                 \
    }                                                                         \
    _Pragma("unroll") for (int mt = 0; mt < 2; ++mt)                          \
    _Pragma("unroll") for (int nt = 0; nt < 4; ++nt) {                        \
        *(uint2*)&h2_t[nt * 16 + c][16 * wave + 8 * mt + 2 * q] = make_uint2( \
            pack2(tanh_pre(acc_[mt][nt][0]), tanh_pre(acc_[mt][nt][1])),      \
            pack2(tanh_pre(acc_[mt][nt][2]), tanh_pre(acc_[mt][nt][3])));     \
    }                                                                         \
    __syncthreads();   /* BAR: h2 visible */                                  \
    {                                                                         \
        f32x4 a3_ = b3s;                                                      \
        _Pragma("unroll") for (int ks = 0; ks < 4; ++ks) {                    \
            bf16x8 bh_ = as_frag(                                             \
                *(const uint4*)&h2_t[wave * 16 + c][16 * ks + 4 * q]);        \
            a3_ = __builtin_amdgcn_mfma_f32_16x16x32_bf16(                    \
                w3f[ks], bh_, a3_, 0, 0, 0);                                  \
        }                                                                     \
        (O0) = a3_[0]; (O1) = a3_[1]; (O2) = a3_[2]; (O3) = a3_[3];           \
    }                                                                         \
} while (0)

// One-time weight prep: convert + transpose + pre-scale into fragment order,
// and zero the output (16384 f32) so integ's atomicAdds start from 0.
// 22528 weight elements, grid 88x256 exact; threads < 16384 also zero out[].
__global__ void __launch_bounds__(256)
prep_kernel(const float* __restrict__ W1, const float* __restrict__ b1,
            const float* __restrict__ W2, const float* __restrict__ W3,
            __bf16* __restrict__ ws, float* __restrict__ out)
{
    const int i = blockIdx.x * 256 + threadIdx.x;
    if (i < 16384) {
        out[i] = 0.0f;
        // W2T[u][k] = W2[k][u] * S   (u = i>>7, k = i&127)
        const int u = i >> 7, k = i & 127;
        ws[i] = (__bf16)(W2[(k << 7) + u] * TANH_SCALE);
    } else if (i < 20480) {
        // W1T[u][k], k=0..31: rows 0..19 = W1*S, row 20 = b1*S, 21..31 = 0
        const int j = i - 16384;
        const int u = j >> 5, k = j & 31;
        const float v = (k < 20) ? W1[(k << 7) + u] * TANH_SCALE
                                 : ((k == 20) ? b1[u] * TANH_SCALE : 0.0f);
        ws[i] = (__bf16)v;
    } else {
        // W3T[c][k] = W3[k][c]  (c = j>>7, k = j&127), unscaled
        const int j = i - 20480;
        const int cc = j >> 7, k = j & 127;
        ws[i] = (__bf16)W3[(k << 4) + cc];
    }
}

__global__ void __launch_bounds__(256, 4)
integ_kernel(const float* __restrict__ sp, const float* __restrict__ Wp,
             const float* __restrict__ b2, const float* __restrict__ b3,
             const __bf16* __restrict__ wsw, float* __restrict__ out)
{
    // 39936 B arena -> 4 blocks/CU (4 x 39936 = 159744 <= 163840):
    //   xs_t 0..5119 | h1_t 5120..22527 | h2_t 22528..39935
    //   [done] parts (64x20 f32) overlays h1_t region
    __shared__ __align__(16) unsigned char smem[39936];
    unsigned int (*xs_t)[20] = (unsigned int (*)[20])smem;
    unsigned int (*h1_t)[68] = (unsigned int (*)[68])(smem + 5120);
    unsigned int (*h2_t)[68] = (unsigned int (*)[68])(smem + 22528);
    float* parts = (float*)(smem + 5120);

    const int tid  = threadIdx.x;
    const int wave = tid >> 6;
    const int lane = tid & 63;
    const int q    = lane >> 4;
    const int c    = lane & 15;
    const int wrow = wave * 16 + c;
    const int pt   = blockIdx.x * 64 + wrow;   // 656*64 = 41984 exact

    // ---- early global loads ----
    const float4 xv = *(const float4*)(sp + (size_t)pt * 20 + 4 * q);
    const float4 u4 = *(const float4*)(sp + (size_t)pt * 20 + 16);
    const float  wp = Wp[pt];
    float4 t0 = *(const float4*)(b2 + 32 * wave + 4 * q);
    float4 t1 = *(const float4*)(b2 + 32 * wave + 16 + 4 * q);
    float4 t3 = *(const float4*)(b3 + 4 * q);
    const f32x4 b2s0 = {t0.x * TANH_SCALE, t0.y * TANH_SCALE,
                        t0.z * TANH_SCALE, t0.w * TANH_SCALE};
    const f32x4 b2s1 = {t1.x * TANH_SCALE, t1.y * TANH_SCALE,
                        t1.z * TANH_SCALE, t1.w * TANH_SCALE};
    const f32x4 b3s  = {t3.x, t3.y, t3.z, t3.w};

    // ---- fragment loads straight from prepped global (L2-resident) ----
    const __bf16* w2t = wsw;            // [u][k] 128x128
    const __bf16* w1t = wsw + 16384;    // [u][k] 128x32
    const __bf16* w3t = wsw + 20480;    // [c][k]  16x128

    bf16x8 w1f[2];
    bf16x8 w2f[2][4];   // 32 VGPRs
    bf16x8 w3f[4];
#pragma unroll
    for (int mt = 0; mt < 2; ++mt) {
        const int ucol = 32 * wave + 16 * mt + c;
        w1f[mt] = as_frag(*(const uint4*)&w1t[(ucol << 5) + (q << 3)]);
#pragma unroll
        for (int ks = 0; ks < 4; ++ks)
            w2f[mt][ks] =
                as_frag(*(const uint4*)&w2t[(ucol << 7) + (ks << 5) + (q << 3)]);
    }
#pragma unroll
    for (int ks = 0; ks < 4; ++ks)
        w3f[ks] = as_frag(*(const uint4*)&w3t[(c << 7) + (ks << 5) + (q << 3)]);

    // ---- static xs parts: u dims 16..19, 1.0 at dim 20, zeros 21..31 ----
    // (FEVAL's first __syncthreads covers these writes.)
    if (q == 0) {
        *(uint2*)&xs_t[wrow][8] = make_uint2(pack2(u4.x, u4.y), pack2(u4.z, u4.w));
    } else if (q == 1) {
        *(uint2*)&xs_t[wrow][10] = make_uint2(pack2(1.0f, 0.0f), 0u);
    } else if (q == 2) {
        *(uint4*)&xs_t[wrow][12] = make_uint4(0u, 0u, 0u, 0u);
    }

    // ---- forward Euler: X += h * f(X) ----
    float X0 = xv.x, X1 = xv.y, X2 = xv.z, X3 = xv.w;
    float k10, k11, k12, k13;
    FEVAL(X0, X1, X2, X3, k10, k11, k12, k13);
    X0 = __builtin_fmaf((float)DT, k10, X0);
    X1 = __builtin_fmaf((float)DT, k11, X1);
    X2 = __builtin_fmaf((float)DT, k12, X2);
    X3 = __builtin_fmaf((float)DT, k13, X3);

    // ---- segmented UT reduce: partials to LDS (h1 region is dead now) ----
    *(float4*)&parts[wrow * 20 + 4 * q] =
        make_float4(wp * X0, wp * X1, wp * X2, wp * X3);

    __syncthreads();   // BAR: partials visible

    // 64 consecutive points span <= 3 batches of 41
    if (tid < 48) {
        const int base = blockIdx.x * 64;
        const int bi = tid >> 4, d = tid & 15;
        const int batch = base / 41 + bi;
        if (batch < 1024) {
            int lo = batch * 41, hi = lo + 41;
            lo = (lo < base) ? base : lo;
            hi = (hi > base + 64) ? base + 64 : hi;
            if (lo < hi) {
                float s = 0.0f;
                for (int p = lo; p < hi; ++p) s += parts[(p - base) * 20 + d];
                atomicAdd(out + batch * 16 + d, s);
            }
        }
    }
}

extern "C" void kernel_launch(void* const* d_in, const int* in_sizes, int n_in,
                              void* d_out, int out_size, void* d_ws, size_t ws_size,
                              hipStream_t stream) {
    (void)in_sizes; (void)n_in; (void)ws_size; (void)out_size;
    prep_kernel<<<dim3(88), dim3(256), 0, stream>>>(
        (const float*)d_in[2], (const float*)d_in[3],
        (const float*)d_in[4], (const float*)d_in[6],
        (__bf16*)d_ws, (float*)d_out);
    integ_kernel<<<dim3(656), dim3(256), 0, stream>>>(
        (const float*)d_in[0], (const float*)d_in[1],
        (const float*)d_in[5], (const float*)d_in[7],
        (const __bf16*)d_ws, (float*)d_out);
}